// Round 7
// baseline (410.315 us; speedup 1.0000x reference)
//
#include <hip/hip_runtime.h>
#include <stdint.h>

// VQ-VAE nearest-codebook index: N=32768 queries, D=64, K=8192 codes.
// SINGLE fused kernel (grid 512, plain launch, own device-scope spin barriers):
//   phase 0: codebook hi/lo bf16 split + norms (blocks 0..255)
//   phase 1: bf16x3 MFMA (split-K=2), best+second-best per query  [R6-proven math]
//   phase 2: merge 2 partitions, write indices, flag gap<EPS queries
//   phase 3: exact fp32 recompute, k-tiled: codes staged ONCE per block in LDS
//            (transposed, conflict-free) -> codebook traffic 16 MB, not cnt*2MB
//   phase 4: write back exact answers
// Barrier counters + cnt zeroed via hipMemsetAsync (capture-safe).
// Co-residency proof: launch_bounds(256,2) => >=2 blocks/CU => >=512 resident.
// Fallback: R6 5-kernel path (proven, 246us) if ws too small.

#define N_TOTAL 32768
#define K_CODES 8192
#define EPS_GAP 0.015f
#define GRID_F  512

typedef __attribute__((ext_vector_type(16))) float  floatx16;
typedef __attribute__((ext_vector_type(8)))  __bf16 bf16x8;

// ---- workspace layout (bytes) ----
#define O_C2    0u          // 8192 f32
#define O_CBSW  32768u      // [256 kBlk][16 cg][32 m][8 bf16] = 2 MB
#define O_PS1   2129920u    // 4*32768 f32 (fused uses first 2 partitions)
#define O_PS2   2654208u
#define O_PI1   3178496u
#define O_CNT   3702784u    // cnt @ +0, barrier counters @ +16..+31
#define O_LIST  3703040u    // 32768 int
#define O_SLOT  3834112u    // 32768 u64
#define WS_NEED 4096256u

#if defined(__has_builtin)
#if __has_builtin(__builtin_amdgcn_fmed3f)
#define MED3(a, b, c) __builtin_amdgcn_fmed3f((a), (b), (c))
#endif
#endif
#ifndef MED3
#define MED3(a, b, c) fminf((c), fmaxf((a), (b)))
#endif

__device__ __forceinline__ unsigned int fkey(float s) {
    unsigned int u = __float_as_uint(s);
    return (u & 0x80000000u) ? ~u : (u | 0x80000000u);
}

__device__ __forceinline__ void load_lds16(const void* g, void* l) {
    __builtin_amdgcn_global_load_lds(
        (const __attribute__((address_space(1))) unsigned int*)g,
        (__attribute__((address_space(3))) unsigned int*)l, 16, 0, 0);
}

// device-scope grid barrier; counter pre-zeroed by hipMemsetAsync, single-use.
__device__ __forceinline__ void grid_bar(int* bar) {
    __syncthreads();
    if (threadIdx.x == 0) {
        __threadfence();
        atomicAdd(bar, 1);
        while (__hip_atomic_load(bar, __ATOMIC_RELAXED, __HIP_MEMORY_SCOPE_AGENT) < GRID_F)
            __builtin_amdgcn_s_sleep(1);
        __threadfence();
    }
    __syncthreads();
}

__global__ __launch_bounds__(256, 2) void vq_fused(
    const float4* __restrict__ lat, const float4* __restrict__ cb,
    int* __restrict__ out, float* __restrict__ c2, uint4* __restrict__ cbSw,
    float* __restrict__ pS1, float* __restrict__ pS2, int* __restrict__ pI1,
    int* __restrict__ cntbar, int* __restrict__ list,
    unsigned long long* __restrict__ slot) {
    __shared__ uint4 Bs[2048];      // 32 KB, reused by phases 0/1/3
    __shared__ float c2s[128];
    const int tid = threadIdx.x;
    int* cnt = cntbar;
    int* bars = cntbar + 4;

    // ---------------- phase 0: prep (blocks 0..255) ----------------
    if (blockIdx.x < 256) {
        float* red = (float*)Bs;
        const int m = tid & 31, g = tid >> 5;
        const int rb = blockIdx.x;
        float4 a = cb[(size_t)(rb * 32 + m) * 16 + g * 2];
        float4 b = cb[(size_t)(rb * 32 + m) * 16 + g * 2 + 1];
        float x[8] = {a.x, a.y, a.z, a.w, b.x, b.y, b.z, b.w};
        bf16x8 hv, lv;
        float ss = 0.f;
#pragma unroll
        for (int i = 0; i < 8; ++i) {
            float v  = x[i];
            __bf16 hb = (__bf16)v;           // RNE
            float r  = v - (float)hb;
            hv[i] = hb;
            lv[i] = (__bf16)r;
            ss += v * v;
        }
        cbSw[(size_t)rb * 512 + g * 32 + m]       = __builtin_bit_cast(uint4, hv);
        cbSw[(size_t)rb * 512 + (8 + g) * 32 + m] = __builtin_bit_cast(uint4, lv);
        red[tid] = ss;
        __syncthreads();
        if (tid < 32) {
            float s = 0.f;
#pragma unroll
            for (int gg = 0; gg < 8; ++gg) s += red[tid + 32 * gg];
            c2[rb * 32 + tid] = s;
        }
    }
    grid_bar(&bars[0]);

    // ---------------- phase 1: MFMA main (split-K=2) ----------------
    {
        const int wr = tid >> 6, lane = tid & 63;
        const int m = lane & 31, h = lane >> 5;
        const int qblk = blockIdx.x >> 1, part = blockIdx.x & 1;
        const int q = qblk * 128 + wr * 32 + m;

        bf16x8 aH[4], aL[4];
#pragma unroll
        for (int c = 0; c < 4; ++c) {
            float4 v0 = lat[(size_t)q * 16 + c * 4 + h * 2];
            float4 v1 = lat[(size_t)q * 16 + c * 4 + h * 2 + 1];
            float x[8] = {v0.x, v0.y, v0.z, v0.w, v1.x, v1.y, v1.z, v1.w};
#pragma unroll
            for (int j = 0; j < 8; ++j) {
                float v  = x[j];
                __bf16 hb = (__bf16)v;
                aH[c][j] = hb;
                aL[c][j] = (__bf16)(v - (float)hb);
            }
        }

        float s1[16], s2[16]; int i1[16];
#pragma unroll
        for (int r = 0; r < 16; ++r) { s1[r] = 3e38f; s2[r] = 3e38f; i1[r] = 0; }

        const int kBase = part * 4096;
        for (int stage = 0; stage < 32; ++stage) {
            const int rbBase = part * 128 + stage * 4;
            __syncthreads();
#pragma unroll
            for (int i = 0; i < 8; ++i)
                load_lds16(&cbSw[(size_t)rbBase * 512 + wr * 64 + 256 * i + lane],
                           &Bs[wr * 64 + 256 * i]);
            __syncthreads();

#pragma unroll
            for (int kb = 0; kb < 4; ++kb) {
                const int col = kBase + stage * 128 + kb * 32 + m;
                const float cc = c2[col];
                floatx16 acc;
#pragma unroll
                for (int r = 0; r < 16; ++r) acc[r] = 0.f;
#pragma unroll
                for (int c = 0; c < 4; ++c) {
                    bf16x8 bH = __builtin_bit_cast(bf16x8, Bs[kb * 512 + (c * 2 + h) * 32 + m]);
                    bf16x8 bL = __builtin_bit_cast(bf16x8, Bs[kb * 512 + (8 + c * 2 + h) * 32 + m]);
                    acc = __builtin_amdgcn_mfma_f32_32x32x16_bf16(aH[c], bH, acc, 0, 0, 0);
                    acc = __builtin_amdgcn_mfma_f32_32x32x16_bf16(aL[c], bH, acc, 0, 0, 0);
                    acc = __builtin_amdgcn_mfma_f32_32x32x16_bf16(aH[c], bL, acc, 0, 0, 0);
                }
#pragma unroll
                for (int r = 0; r < 16; ++r) {
                    float s = fmaf(-2.f, acc[r], cc);
                    s2[r] = MED3(s, s1[r], s2[r]);     // = min(s2, max(s, s1))
                    bool lt = s < s1[r];
                    i1[r] = lt ? col : i1[r];
                    s1[r] = lt ? s : s1[r];
                }
            }
        }

#pragma unroll
        for (int mask = 1; mask <= 16; mask <<= 1) {
#pragma unroll
            for (int r = 0; r < 16; ++r) {
                float o1 = __shfl_xor(s1[r], mask);
                float o2 = __shfl_xor(s2[r], mask);
                int   oi = __shfl_xor(i1[r], mask);
                float n2 = fminf(fminf(s2[r], o2), fmaxf(s1[r], o1));
                bool take = (o1 < s1[r]) || (o1 == s1[r] && oi < i1[r]);
                s1[r] = take ? o1 : s1[r];
                i1[r] = take ? oi : i1[r];
                s2[r] = n2;
            }
        }

        if (m == 0) {
            const int qb = qblk * 128 + wr * 32;
            const int o0 = part * N_TOTAL;
#pragma unroll
            for (int r = 0; r < 16; ++r) {
                int row = (r & 3) + 8 * (r >> 2) + 4 * h;   // C/D layout row
                int qq = qb + row;
                pS1[o0 + qq] = s1[r];
                pS2[o0 + qq] = s2[r];
                pI1[o0 + qq] = i1[r];
            }
        }
    }
    grid_bar(&bars[1]);

    // ---------------- phase 2: merge 2 partitions + flag ----------------
    {
        int q = blockIdx.x * 256 + tid;
        if (q < N_TOTAL) {
            float a1 = pS1[q],           a2 = pS2[q];           int ai = pI1[q];
            float b1 = pS1[N_TOTAL + q], b2 = pS2[N_TOTAL + q]; int bi = pI1[N_TOTAL + q];
            bool take = (b1 < a1) || (b1 == a1 && bi < ai);
            float g1 = take ? b1 : a1;
            int   gi = take ? bi : ai;
            float g2 = fminf(fminf(a2, b2), fmaxf(a1, b1));
            out[q] = gi;
            if (g2 - g1 < EPS_GAP) {
                int e = atomicAdd(cnt, 1);
                list[e] = q;
                slot[e] = 0xFFFFFFFFFFFFFFFFull;
            }
        }
    }
    grid_bar(&bars[2]);

    // ---------------- phase 3: exact fp32, k-tiled shared codebook ----------------
    {
        const int n = *cnt;
        if (n > 0) {
            const int ks   = blockIdx.x & 63;   // 128-code slice
            const int egrp = blockIdx.x >> 6;   // 8 e-groups
            float* CbT = (float*)Bs;            // [64 d][128 code] = 32 KB
            for (int i = tid; i < 2048; i += 256) {
                int code = i >> 4, d4 = i & 15;
                float4 v = cb[(size_t)(ks * 128 + code) * 16 + d4];
                CbT[(d4 * 4 + 0) * 128 + code] = v.x;
                CbT[(d4 * 4 + 1) * 128 + code] = v.y;
                CbT[(d4 * 4 + 2) * 128 + code] = v.z;
                CbT[(d4 * 4 + 3) * 128 + code] = v.w;
            }
            if (tid < 128) c2s[tid] = c2[ks * 128 + tid];
            __syncthreads();

            const int code = tid >> 1, dh = tid & 1;
            for (int e = egrp; e < n; e += 8) {
                const int qq = list[e];
                const float4* qp = lat + (size_t)qq * 16 + dh * 8;
                float dot = 0.f;
#pragma unroll
                for (int j = 0; j < 8; ++j) {
                    float4 qv = qp[j];
                    dot += qv.x * CbT[(dh * 32 + j * 4 + 0) * 128 + code]
                         + qv.y * CbT[(dh * 32 + j * 4 + 1) * 128 + code]
                         + qv.z * CbT[(dh * 32 + j * 4 + 2) * 128 + code]
                         + qv.w * CbT[(dh * 32 + j * 4 + 3) * 128 + code];
                }
                dot += __shfl_xor(dot, 1);          // combine D-halves (lane pair)
                float s = c2s[code] - 2.f * dot;
                unsigned long long p =
                    ((unsigned long long)fkey(s) << 32) | (unsigned)(ks * 128 + code);
#pragma unroll
                for (int mask = 1; mask <= 32; mask <<= 1) {
                    unsigned long long o = __shfl_xor(p, mask);
                    p = o < p ? o : p;
                }
                if ((tid & 63) == 0) atomicMin(&slot[e], p);
            }
        }
    }
    grid_bar(&bars[3]);

    // ---------------- phase 4: write back flagged ----------------
    {
        int t = blockIdx.x * 256 + tid;
        if (t < *cnt) out[list[t]] = (int)(slot[t] & 0xFFFFFFFFull);
    }
}

// ================= fallback: R6-proven 5-kernel path =================
__global__ __launch_bounds__(256) void vq_prep(
    const float4* __restrict__ cb, uint4* __restrict__ cbSw,
    float* __restrict__ c2, int* __restrict__ cnt) {
    __shared__ float red[256];
    const int m = threadIdx.x & 31, g = threadIdx.x >> 5;
    const int rb = blockIdx.x;
    if (rb == 0 && threadIdx.x == 0) *cnt = 0;
    float4 a = cb[(size_t)(rb * 32 + m) * 16 + g * 2];
    float4 b = cb[(size_t)(rb * 32 + m) * 16 + g * 2 + 1];
    float x[8] = {a.x, a.y, a.z, a.w, b.x, b.y, b.z, b.w};
    bf16x8 hv, lv;
    float ss = 0.f;
#pragma unroll
    for (int i = 0; i < 8; ++i) {
        float v  = x[i];
        __bf16 hb = (__bf16)v;
        float r  = v - (float)hb;
        hv[i] = hb;
        lv[i] = (__bf16)r;
        ss += v * v;
    }
    cbSw[(size_t)rb * 512 + g * 32 + m]       = __builtin_bit_cast(uint4, hv);
    cbSw[(size_t)rb * 512 + (8 + g) * 32 + m] = __builtin_bit_cast(uint4, lv);
    red[threadIdx.x] = ss;
    __syncthreads();
    if (threadIdx.x < 32) {
        float s = 0.f;
#pragma unroll
        for (int gg = 0; gg < 8; ++gg) s += red[threadIdx.x + 32 * gg];
        c2[rb * 32 + threadIdx.x] = s;
    }
}

__global__ __launch_bounds__(256, 2) void vq_mfma(
    const float4* __restrict__ lat, const uint4* __restrict__ cbSw,
    const float* __restrict__ c2,
    float* __restrict__ pS1, float* __restrict__ pS2, int* __restrict__ pI1) {
    __shared__ uint4 Bs[2048];
    const int tid = threadIdx.x;
    const int wr = tid >> 6, lane = tid & 63;
    const int m = lane & 31, h = lane >> 5;
    const int q = blockIdx.x * 128 + wr * 32 + m;
    bf16x8 aH[4], aL[4];
#pragma unroll
    for (int c = 0; c < 4; ++c) {
        float4 v0 = lat[(size_t)q * 16 + c * 4 + h * 2];
        float4 v1 = lat[(size_t)q * 16 + c * 4 + h * 2 + 1];
        float x[8] = {v0.x, v0.y, v0.z, v0.w, v1.x, v1.y, v1.z, v1.w};
#pragma unroll
        for (int j = 0; j < 8; ++j) {
            float v  = x[j];
            __bf16 hb = (__bf16)v;
            aH[c][j] = hb;
            aL[c][j] = (__bf16)(v - (float)hb);
        }
    }
    float s1[16], s2[16]; int i1[16];
#pragma unroll
    for (int r = 0; r < 16; ++r) { s1[r] = 3e38f; s2[r] = 3e38f; i1[r] = 0; }
    const int kBase = blockIdx.y * 2048;
    for (int stage = 0; stage < 16; ++stage) {
        const int rbBase = (kBase >> 5) + stage * 4;
        __syncthreads();
#pragma unroll
        for (int i = 0; i < 8; ++i)
            load_lds16(&cbSw[(size_t)rbBase * 512 + wr * 64 + 256 * i + lane],
                       &Bs[wr * 64 + 256 * i]);
        __syncthreads();
#pragma unroll
        for (int kb = 0; kb < 4; ++kb) {
            const int col = kBase + stage * 128 + kb * 32 + m;
            const float cc = c2[col];
            floatx16 acc;
#pragma unroll
            for (int r = 0; r < 16; ++r) acc[r] = 0.f;
#pragma unroll
            for (int c = 0; c < 4; ++c) {
                bf16x8 bH = __builtin_bit_cast(bf16x8, Bs[kb * 512 + (c * 2 + h) * 32 + m]);
                bf16x8 bL = __builtin_bit_cast(bf16x8, Bs[kb * 512 + (8 + c * 2 + h) * 32 + m]);
                acc = __builtin_amdgcn_mfma_f32_32x32x16_bf16(aH[c], bH, acc, 0, 0, 0);
                acc = __builtin_amdgcn_mfma_f32_32x32x16_bf16(aL[c], bH, acc, 0, 0, 0);
                acc = __builtin_amdgcn_mfma_f32_32x32x16_bf16(aH[c], bL, acc, 0, 0, 0);
            }
#pragma unroll
            for (int r = 0; r < 16; ++r) {
                float s = fmaf(-2.f, acc[r], cc);
                s2[r] = MED3(s, s1[r], s2[r]);
                bool lt = s < s1[r];
                i1[r] = lt ? col : i1[r];
                s1[r] = lt ? s : s1[r];
            }
        }
    }
#pragma unroll
    for (int mask = 1; mask <= 16; mask <<= 1) {
#pragma unroll
        for (int r = 0; r < 16; ++r) {
            float o1 = __shfl_xor(s1[r], mask);
            float o2 = __shfl_xor(s2[r], mask);
            int   oi = __shfl_xor(i1[r], mask);
            float n2 = fminf(fminf(s2[r], o2), fmaxf(s1[r], o1));
            bool take = (o1 < s1[r]) || (o1 == s1[r] && oi < i1[r]);
            s1[r] = take ? o1 : s1[r];
            i1[r] = take ? oi : i1[r];
            s2[r] = n2;
        }
    }
    if (m == 0) {
        const int qb = blockIdx.x * 128 + wr * 32;
        const int o0 = blockIdx.y * N_TOTAL;
#pragma unroll
        for (int r = 0; r < 16; ++r) {
            int row = (r & 3) + 8 * (r >> 2) + 4 * h;
            int qq = qb + row;
            pS1[o0 + qq] = s1[r];
            pS2[o0 + qq] = s2[r];
            pI1[o0 + qq] = i1[r];
        }
    }
}

__global__ void vq_merge4(const float* __restrict__ pS1, const float* __restrict__ pS2,
                          const int* __restrict__ pI1, int* __restrict__ out,
                          int* __restrict__ cnt, int* __restrict__ list,
                          unsigned long long* __restrict__ slot) {
    int q = blockIdx.x * 256 + threadIdx.x;
    float g1 = 3e38f, g2 = 3e38f;
    int   gi = 0x7FFFFFFF;
#pragma unroll
    for (int p = 0; p < 4; ++p) {
        float s1p = pS1[p * N_TOTAL + q];
        float s2p = pS2[p * N_TOTAL + q];
        int   i1p = pI1[p * N_TOTAL + q];
        bool take = (s1p < g1) || (s1p == g1 && i1p < gi);
        g2 = fminf(g2, fminf(s2p, take ? g1 : s1p));
        if (take) { g1 = s1p; gi = i1p; }
    }
    out[q] = gi;
    if (g2 - g1 < EPS_GAP) {
        int e = atomicAdd(cnt, 1);
        list[e] = q;
        slot[e] = 0xFFFFFFFFFFFFFFFFull;
    }
}

__global__ __launch_bounds__(256) void vq_exact2(
    const float4* __restrict__ lat, const float4* __restrict__ cb,
    const float* __restrict__ c2, const int* __restrict__ cnt,
    const int* __restrict__ list, unsigned long long* __restrict__ slot) {
    __shared__ float qv[4][64];
    const int n = *cnt;
    const int totalChunks = n * 8;
    const int wInB = threadIdx.x >> 6;
    const int lane = threadIdx.x & 63;
    for (int base = blockIdx.x * 4; base < totalChunks; base += gridDim.x * 4) {
        const int c = base + wInB;
        const bool act = c < totalChunks;
        int e = 0, q = 0, kb = 0;
        if (act) { e = c >> 3; q = list[e]; kb = (c & 7) << 10; }
        __syncthreads();
        if (act && lane < 16) {
            float4 v = lat[(size_t)q * 16 + lane];
            *(float4*)&qv[wInB][lane * 4] = v;
        }
        __syncthreads();
        if (act) {
            float best = 3e38f; int bi = 0;
#pragma unroll 2
            for (int i = 0; i < 16; ++i) {
                const int k = kb + i * 64 + lane;
                float dot = 0.f;
#pragma unroll
                for (int d4 = 0; d4 < 16; ++d4) {
                    float4 cv = cb[(size_t)k * 16 + d4];
                    dot += qv[wInB][d4 * 4 + 0] * cv.x + qv[wInB][d4 * 4 + 1] * cv.y
                         + qv[wInB][d4 * 4 + 2] * cv.z + qv[wInB][d4 * 4 + 3] * cv.w;
                }
                float s = c2[k] - 2.f * dot;
                if (s < best) { best = s; bi = k; }
            }
            unsigned long long p = ((unsigned long long)fkey(best) << 32) | (unsigned)bi;
#pragma unroll
            for (int mask = 1; mask <= 32; mask <<= 1) {
                unsigned long long o = __shfl_xor(p, mask);
                p = o < p ? o : p;
            }
            if (lane == 0) atomicMin(&slot[e], p);
        }
    }
}

__global__ void vq_write(const int* __restrict__ cnt, const int* __restrict__ list,
                         const unsigned long long* __restrict__ slot,
                         int* __restrict__ out) {
    int t = blockIdx.x * 256 + threadIdx.x;
    if (t < *cnt) out[list[t]] = (int)(slot[t] & 0xFFFFFFFFull);
}

extern "C" void kernel_launch(void* const* d_in, const int* in_sizes, int n_in,
                              void* d_out, int out_size, void* d_ws, size_t ws_size,
                              hipStream_t stream) {
    const float4* lat = (const float4*)d_in[0];
    const float4* cb  = (const float4*)d_in[1];
    int* out = (int*)d_out;
    char* ws = (char*)d_ws;

    float* c2   = (float*)(ws + O_C2);
    uint4* cbSw = (uint4*)(ws + O_CBSW);
    float* pS1  = (float*)(ws + O_PS1);
    float* pS2  = (float*)(ws + O_PS2);
    int*   pI1  = (int*)(ws + O_PI1);
    int*   cntbar = (int*)(ws + O_CNT);
    int*   list = (int*)(ws + O_LIST);
    unsigned long long* slot = (unsigned long long*)(ws + O_SLOT);

    if (ws_size >= WS_NEED) {
        hipMemsetAsync(cntbar, 0, 32, stream);   // cnt + 4 barrier counters
        vq_fused<<<GRID_F, 256, 0, stream>>>(lat, cb, out, c2, cbSw,
                                             pS1, pS2, pI1, cntbar, list, slot);
    } else {
        // R6-proven multi-kernel fallback (split-K=4)
        vq_prep<<<256, 256, 0, stream>>>(cb, cbSw, c2, cntbar);
        vq_mfma<<<dim3(256, 4), 256, 0, stream>>>(lat, cbSw, c2, pS1, pS2, pI1);
        vq_merge4<<<128, 256, 0, stream>>>(pS1, pS2, pI1, out, cntbar, list, slot);
        vq_exact2<<<1024, 256, 0, stream>>>(lat, cb, c2, cntbar, list, slot);
        vq_write<<<128, 256, 0, stream>>>(cntbar, list, slot, out);
    }
}